// Round 1
// baseline (113.537 us; speedup 1.0000x reference)
//
#include <hip/hip_runtime.h>

// CRF NLL on MI355X — round 11: 4-way chunk ILP + 2-level in-block merge tree,
// prep kernel eliminated (A-frags in-block, gold in combine, zero in chunks).
// Each chunk (64 steps) = four independent 16-step quarter-products Ha..Hd
// advanced interleaved (4 dependency chains in flight per wave), then merged
// in-block: P1 = Hb*Ha, P2 = Hd*Hc (parallel), R = P2*P1. Exponent renorm at
// each merge level uses wave-max exponent (safe for identity/dead chunks).

#define SS 512
#define TT 64
#define CC 8
#define KCH 64
#define START_TAG 62
#define END_TAG 63
#define LOG2E_F 1.44269504088896340736f
#define LN2_F 0.69314718055994530942f

#define WS_ECOL_OFF 4194304
#define MSTR 72   // merge-LDS row stride in halfs (16B-aligned rows, bank-spread)

typedef float v4f __attribute__((ext_vector_type(4)));
typedef _Float16 h4 __attribute__((ext_vector_type(4)));
typedef __fp16 c2 __attribute__((ext_vector_type(2)));
union H4u { h4 v; struct { c2 lo, hi; } p; };

// ---------------- per-step core (r9-proven, unchanged) ----------------
__device__ __forceinline__ void cstep(const h4 (&A)[4][4], h4 (&B)[4],
                                      float* __restrict__ emb, float& fq,
                                      const float* __restrict__ fcol, int tload,
                                      int q, int l, int& esum, int& esc) {
    v4f z = {0.f, 0.f, 0.f, 0.f};
    v4f D[4];
#pragma unroll
    for (int mt = 0; mt < 4; ++mt) {
        v4f a = __builtin_amdgcn_mfma_f32_16x16x16f16(A[mt][0], B[0], z, 0, 0, 0);
        a = __builtin_amdgcn_mfma_f32_16x16x16f16(A[mt][1], B[1], a, 0, 0, 0);
        v4f b = __builtin_amdgcn_mfma_f32_16x16x16f16(A[mt][2], B[2], z, 0, 0, 0);
        b = __builtin_amdgcn_mfma_f32_16x16x16f16(A[mt][3], B[3], b, 0, 0, 0);
        D[mt] = a + b;
    }
    v4f em[4];
#pragma unroll
    for (int mt = 0; mt < 4; ++mt) em[mt] = *(const v4f*)(emb + 16 * mt + 4 * q);
    emb[l] = __builtin_amdgcn_exp2f(fq * LOG2E_F);
    fq = fcol[(size_t)tload * TT];
    esum += esc;
    float scf = __uint_as_float((unsigned)(127 - esc) << 23);
    v4f qs[4];
#pragma unroll
    for (int mt = 0; mt < 4; ++mt) qs[mt] = D[mt] * (em[mt] * scf);
#pragma unroll
    for (int mt = 0; mt < 4; ++mt) {
        H4u u;
        u.p.lo = __builtin_amdgcn_cvt_pkrtz(qs[mt].x, qs[mt].y);
        u.p.hi = __builtin_amdgcn_cvt_pkrtz(qs[mt].z, qs[mt].w);
        B[mt] = u.v;
    }
    unsigned u0 = (unsigned)__builtin_amdgcn_readfirstlane((int)__float_as_uint(qs[0].x));
    esc = (int)((u0 >> 23) & 255u) - 127;
}

// ---------------- chunk kernel: 4 sub-chains x 16 steps ----------------
__global__ __launch_bounds__(256, 1)
void crf_chunks(const float* __restrict__ feats, const float* __restrict__ trans,
                const int* __restrict__ mask, unsigned short* __restrict__ Pg,
                int* __restrict__ Eg, float* __restrict__ out) {
    __shared__ float em[4][4][2][TT];
    __shared__ __align__(16) _Float16 mldB[TT * MSTR];
    __shared__ __align__(16) _Float16 mldD[TT * MSTR];
    __shared__ int ebuf[12];

    const int blk = blockIdx.x;
    const int chain = blk >> 3, c = blk & 7;
    const int tid = threadIdx.x;
    const int w = tid >> 6, l = tid & 63;
    const int n16 = l & 15, q = l >> 4;
    const int ncol = 16 * w + n16;

    if (blk == 0 && tid == 0) out[0] = 0.f;  // zero accumulator (combine runs after)

    // A = E^T stationary frags, computed in-block from trans (one-time)
    h4 A[4][4];
#pragma unroll
    for (int mt = 0; mt < 4; ++mt)
#pragma unroll
        for (int ks = 0; ks < 4; ++ks) {
            h4 a;
#pragma unroll
            for (int e = 0; e < 4; ++e)
                a[e] = (_Float16)__builtin_amdgcn_exp2f(
                    trans[(16 * ks + 4 * q + e) * TT + 16 * mt + n16] * LOG2E_F);
            A[mt][ks] = a;
        }

    // chain length L
    const int* mp = mask + chain * SS;
    int msum = 0;
#pragma unroll
    for (int k = 0; k < 8; ++k) msum += mp[k * 64 + l];
#pragma unroll
    for (int s_ = 1; s_ < 64; s_ <<= 1) msum += __shfl_xor(msum, s_, 64);
    const int L = msum;

    const int t0a = 1 + KCH * c;
    const int t0b = t0a + 16, t0c = t0a + 32, t0d = t0a + 48;
    const int base = (L - 1) - KCH * c;
    int nA = base < 0 ? 0 : (base > 16 ? 16 : base);
    int nB = base - 16 < 0 ? 0 : (base - 16 > 16 ? 16 : base - 16);
    int nC = base - 32 < 0 ? 0 : (base - 32 > 16 ? 16 : base - 32);
    int nD = base - 48 < 0 ? 0 : (base - 48 > 16 ? 16 : base - 48);

    // identity inits
    h4 Ba[4], Bb[4], Bc[4], Bd[4];
#pragma unroll
    for (int ks = 0; ks < 4; ++ks) {
        h4 b;
#pragma unroll
        for (int jj = 0; jj < 4; ++jj)
            b[jj] = (_Float16)((16 * ks + 4 * q + jj == ncol) ? 1.f : 0.f);
        Ba[ks] = b; Bb[ks] = b; Bc[ks] = b; Bd[ks] = b;
    }

    // emission pipelines (per sub-chain), 2-step lead
    const float* fcol = feats + (size_t)chain * SS * TT + l;
#define CT(x) ((x) < SS ? (x) : SS - 1)
    em[0][w][0][l] = __builtin_amdgcn_exp2f(fcol[(size_t)CT(t0a) * TT] * LOG2E_F);
    em[0][w][1][l] = __builtin_amdgcn_exp2f(fcol[(size_t)CT(t0a + 1) * TT] * LOG2E_F);
    em[1][w][0][l] = __builtin_amdgcn_exp2f(fcol[(size_t)CT(t0b) * TT] * LOG2E_F);
    em[1][w][1][l] = __builtin_amdgcn_exp2f(fcol[(size_t)CT(t0b + 1) * TT] * LOG2E_F);
    em[2][w][0][l] = __builtin_amdgcn_exp2f(fcol[(size_t)CT(t0c) * TT] * LOG2E_F);
    em[2][w][1][l] = __builtin_amdgcn_exp2f(fcol[(size_t)CT(t0c + 1) * TT] * LOG2E_F);
    em[3][w][0][l] = __builtin_amdgcn_exp2f(fcol[(size_t)CT(t0d) * TT] * LOG2E_F);
    em[3][w][1][l] = __builtin_amdgcn_exp2f(fcol[(size_t)CT(t0d + 1) * TT] * LOG2E_F);
    float fqA0 = fcol[(size_t)CT(t0a + 2) * TT];
    float fqA1 = fcol[(size_t)CT(t0a + 3) * TT];
    float fqB0 = fcol[(size_t)CT(t0b + 2) * TT];
    float fqB1 = fcol[(size_t)CT(t0b + 3) * TT];
    float fqC0 = fcol[(size_t)CT(t0c + 2) * TT];
    float fqC1 = fcol[(size_t)CT(t0c + 3) * TT];
    float fqD0 = fcol[(size_t)CT(t0d + 2) * TT];
    float fqD1 = fcol[(size_t)CT(t0d + 3) * TT];

    int esA = 0, escA = 0, esB = 0, escB = 0;
    int esC = 0, escC = 0, esD = 0, escD = 0;

    if (nD == 16) {  // all four sub-chains full: branch-free hot path
        for (int r = 0; r < 8; ++r) {
            const int s0 = 2 * r;
            cstep(A, Ba, &em[0][w][0][0], fqA0, fcol, CT(t0a + s0 + 4), q, l, esA, escA);
            cstep(A, Bb, &em[1][w][0][0], fqB0, fcol, CT(t0b + s0 + 4), q, l, esB, escB);
            cstep(A, Bc, &em[2][w][0][0], fqC0, fcol, CT(t0c + s0 + 4), q, l, esC, escC);
            cstep(A, Bd, &em[3][w][0][0], fqD0, fcol, CT(t0d + s0 + 4), q, l, esD, escD);
            cstep(A, Ba, &em[0][w][1][0], fqA1, fcol, CT(t0a + s0 + 5), q, l, esA, escA);
            cstep(A, Bb, &em[1][w][1][0], fqB1, fcol, CT(t0b + s0 + 5), q, l, esB, escB);
            cstep(A, Bc, &em[2][w][1][0], fqC1, fcol, CT(t0c + s0 + 5), q, l, esC, escC);
            cstep(A, Bd, &em[3][w][1][0], fqD1, fcol, CT(t0d + s0 + 5), q, l, esD, escD);
        }
    } else {  // boundary chunk: uniform-predicated
        for (int r = 0; r < 8; ++r) {
            const int s0 = 2 * r, s1 = s0 + 1;
            if (s0 < nA) cstep(A, Ba, &em[0][w][0][0], fqA0, fcol, CT(t0a + s0 + 4), q, l, esA, escA);
            if (s0 < nB) cstep(A, Bb, &em[1][w][0][0], fqB0, fcol, CT(t0b + s0 + 4), q, l, esB, escB);
            if (s0 < nC) cstep(A, Bc, &em[2][w][0][0], fqC0, fcol, CT(t0c + s0 + 4), q, l, esC, escC);
            if (s0 < nD) cstep(A, Bd, &em[3][w][0][0], fqD0, fcol, CT(t0d + s0 + 4), q, l, esD, escD);
            if (s1 < nA) cstep(A, Ba, &em[0][w][1][0], fqA1, fcol, CT(t0a + s1 + 4), q, l, esA, escA);
            if (s1 < nB) cstep(A, Bb, &em[1][w][1][0], fqB1, fcol, CT(t0b + s1 + 4), q, l, esB, escB);
            if (s1 < nC) cstep(A, Bc, &em[2][w][1][0], fqC1, fcol, CT(t0c + s1 + 4), q, l, esC, escC);
            if (s1 < nD) cstep(A, Bd, &em[3][w][1][0], fqD1, fcol, CT(t0d + s1 + 4), q, l, esD, escD);
        }
    }
#undef CT

    // ---- merge level 1: P1 = Hb*Ha, P2 = Hd*Hc (parallel) ----
    if (l == 0) { ebuf[w] = esB; ebuf[4 + w] = esD; }
    __syncthreads();
    const int eBmax = max(max(ebuf[0], ebuf[1]), max(ebuf[2], ebuf[3]));
    const int eDmax = max(max(ebuf[4], ebuf[5]), max(ebuf[6], ebuf[7]));
    {
        _Float16 sB = (_Float16)ldexpf(1.f, esB - eBmax);
        _Float16 sD = (_Float16)ldexpf(1.f, esD - eDmax);
        h4 s4B = {sB, sB, sB, sB}, s4D = {sD, sD, sD, sD};
#pragma unroll
        for (int ks = 0; ks < 4; ++ks) {
            h4 vb = Bb[ks] * s4B;
            h4 vd = Bd[ks] * s4D;
#pragma unroll
            for (int jj = 0; jj < 4; ++jj) {
                mldB[(16 * ks + 4 * q + jj) * MSTR + ncol] = vb[jj];
                mldD[(16 * ks + 4 * q + jj) * MSTR + ncol] = vd[jj];
            }
        }
    }
    __syncthreads();
    h4 AHb[4][4], AHd[4][4];
#pragma unroll
    for (int mt = 0; mt < 4; ++mt)
#pragma unroll
        for (int ks = 0; ks < 4; ++ks) {
            AHb[mt][ks] = *(const h4*)(mldB + (16 * mt + n16) * MSTR + 16 * ks + 4 * q);
            AHd[mt][ks] = *(const h4*)(mldD + (16 * mt + n16) * MSTR + 16 * ks + 4 * q);
        }
    v4f z = {0.f, 0.f, 0.f, 0.f};
    v4f P1[4], P2[4];
#pragma unroll
    for (int mt = 0; mt < 4; ++mt) {
        v4f a = __builtin_amdgcn_mfma_f32_16x16x16f16(AHb[mt][0], Ba[0], z, 0, 0, 0);
        a = __builtin_amdgcn_mfma_f32_16x16x16f16(AHb[mt][1], Ba[1], a, 0, 0, 0);
        v4f b = __builtin_amdgcn_mfma_f32_16x16x16f16(AHb[mt][2], Ba[2], z, 0, 0, 0);
        b = __builtin_amdgcn_mfma_f32_16x16x16f16(AHb[mt][3], Ba[3], b, 0, 0, 0);
        P1[mt] = a + b;
        v4f a2 = __builtin_amdgcn_mfma_f32_16x16x16f16(AHd[mt][0], Bc[0], z, 0, 0, 0);
        a2 = __builtin_amdgcn_mfma_f32_16x16x16f16(AHd[mt][1], Bc[1], a2, 0, 0, 0);
        v4f b2 = __builtin_amdgcn_mfma_f32_16x16x16f16(AHd[mt][2], Bc[2], z, 0, 0, 0);
        b2 = __builtin_amdgcn_mfma_f32_16x16x16f16(AHd[mt][3], Bc[3], b2, 0, 0, 0);
        P2[mt] = a2 + b2;
    }
    // wave-max exponent renorm (all entries >= 0)
    float m1 = 0.f, m2 = 0.f;
#pragma unroll
    for (int mt = 0; mt < 4; ++mt) {
        m1 = fmaxf(m1, fmaxf(fmaxf(P1[mt].x, P1[mt].y), fmaxf(P1[mt].z, P1[mt].w)));
        m2 = fmaxf(m2, fmaxf(fmaxf(P2[mt].x, P2[mt].y), fmaxf(P2[mt].z, P2[mt].w)));
    }
#pragma unroll
    for (int m = 1; m < 64; m <<= 1) {
        m1 = fmaxf(m1, __shfl_xor(m1, m, 64));
        m2 = fmaxf(m2, __shfl_xor(m2, m, 64));
    }
    unsigned u1 = (unsigned)__builtin_amdgcn_readfirstlane((int)__float_as_uint(m1));
    unsigned u2 = (unsigned)__builtin_amdgcn_readfirstlane((int)__float_as_uint(m2));
    const int e1c = u1 ? (int)((u1 >> 23) & 255u) - 127 : 0;
    const int e2c = u2 ? (int)((u2 >> 23) & 255u) - 127 : 0;
    const int e1 = esA + eBmax + e1c;   // per-wave exponent of P1 columns
    const int e2 = esC + eDmax + e2c;   // per-wave exponent of P2 columns
    h4 P1h[4], P2h[4];
    {
        float s1f = __uint_as_float((unsigned)(127 - e1c) << 23);
        float s2f = __uint_as_float((unsigned)(127 - e2c) << 23);
#pragma unroll
        for (int mt = 0; mt < 4; ++mt) {
            v4f q1 = P1[mt] * s1f;
            v4f q2 = P2[mt] * s2f;
            H4u ua, ub;
            ua.p.lo = __builtin_amdgcn_cvt_pkrtz(q1.x, q1.y);
            ua.p.hi = __builtin_amdgcn_cvt_pkrtz(q1.z, q1.w);
            ub.p.lo = __builtin_amdgcn_cvt_pkrtz(q2.x, q2.y);
            ub.p.hi = __builtin_amdgcn_cvt_pkrtz(q2.z, q2.w);
            P1h[mt] = ua.v;
            P2h[mt] = ub.v;
        }
    }

    // ---- merge level 2: R = P2 * P1 ----
    if (l == 0) ebuf[8 + w] = e2;
    __syncthreads();  // covers last mldB/mldD reads + ebuf[8..] visibility
    const int e2max = max(max(ebuf[8], ebuf[9]), max(ebuf[10], ebuf[11]));
    {
        _Float16 s2 = (_Float16)ldexpf(1.f, e2 - e2max);
        h4 s4 = {s2, s2, s2, s2};
#pragma unroll
        for (int mt = 0; mt < 4; ++mt) {
            h4 v = P2h[mt] * s4;
#pragma unroll
            for (int jj = 0; jj < 4; ++jj)
                mldB[(16 * mt + 4 * q + jj) * MSTR + ncol] = v[jj];
        }
    }
    __syncthreads();
    h4 AHp[4][4];
#pragma unroll
    for (int mt = 0; mt < 4; ++mt)
#pragma unroll
        for (int ks = 0; ks < 4; ++ks)
            AHp[mt][ks] = *(const h4*)(mldB + (16 * mt + n16) * MSTR + 16 * ks + 4 * q);
    h4 Rf[4];
#pragma unroll
    for (int mt = 0; mt < 4; ++mt) {
        v4f a = __builtin_amdgcn_mfma_f32_16x16x16f16(AHp[mt][0], P1h[0], z, 0, 0, 0);
        a = __builtin_amdgcn_mfma_f32_16x16x16f16(AHp[mt][1], P1h[1], a, 0, 0, 0);
        v4f b = __builtin_amdgcn_mfma_f32_16x16x16f16(AHp[mt][2], P1h[2], z, 0, 0, 0);
        b = __builtin_amdgcn_mfma_f32_16x16x16f16(AHp[mt][3], P1h[3], b, 0, 0, 0);
        v4f d = a + b;
        H4u u;
        u.p.lo = __builtin_amdgcn_cvt_pkrtz(d.x, d.y);
        u.p.hi = __builtin_amdgcn_cvt_pkrtz(d.z, d.w);
        Rf[mt] = u.v;
    }
    // stage R into mldD (its last reads were 2 barriers ago) and copy out
#pragma unroll
    for (int mt = 0; mt < 4; ++mt)
#pragma unroll
        for (int jj = 0; jj < 4; ++jj)
            mldD[(16 * mt + 4 * q + jj) * MSTR + ncol] = Rf[mt][jj];
    __syncthreads();
    {
        const size_t base_ = ((size_t)chain * CC + c) * 4096;
        int r = tid >> 2, cb = tid & 3;
        const uint4* src = (const uint4*)(mldD + r * MSTR + cb * 16);
        uint4* dst = (uint4*)(Pg + base_ + r * TT + cb * 16);
        dst[0] = src[0];
        dst[1] = src[1];
    }
    if (q == 0) Eg[(chain * CC + c) * TT + ncol] = e1 + e2max;
}

// ---------------- combine (forward scan over chunk matrices + gold) ----------------
__global__ __launch_bounds__(64, 1)
void crf_combine(const float* __restrict__ feats, const float* __restrict__ trans,
                 const int* __restrict__ mask, const int* __restrict__ tags,
                 const unsigned short* __restrict__ Pg, const int* __restrict__ Eg,
                 float* __restrict__ out) {
    __shared__ __align__(16) float yl[TT];
    const int chain = blockIdx.x;
    const int j = threadIdx.x;

    // ---- gold score (issued early; overlaps the forward scan) ----
    int msum = 0;
#pragma unroll
    for (int k = 0; k < 8; ++k) msum += mask[chain * SS + 64 * k + j];
#pragma unroll
    for (int m = 1; m < 64; m <<= 1) msum += __shfl_xor(msum, m, 64);
    const int L = msum;

    float g = 0.f;
#pragma unroll
    for (int k = 0; k < 8; ++k) {
        int t = 64 * k + j;
        if (t < L) {
            int cur = tags[chain * SS + t];
            int prev = t ? tags[chain * SS + t - 1] : START_TAG;
            g += feats[(size_t)chain * SS * TT + (size_t)t * TT + cur] + trans[prev * TT + cur];
        }
    }
#pragma unroll
    for (int m = 1; m < 64; m <<= 1) g += __shfl_xor(g, m, 64);

    // ---- forward ----
    float part0 = feats[(size_t)chain * SS * TT + j] + trans[START_TAG * TT + j];
    float M0 = part0;
#pragma unroll
    for (int m = 1; m < 64; m <<= 1) M0 = fmaxf(M0, __shfl_xor(M0, m, 64));
    float x = exp2f((part0 - M0) * LOG2E_F);
    int esumX = 0;

    for (int c = 0; c < CC; ++c) {
        int e = Eg[(chain * CC + c) * TT + j];
        int emax = e;
#pragma unroll
        for (int m = 1; m < 64; m <<= 1) emax = max(emax, __shfl_xor(emax, m, 64));
        yl[j] = ldexpf(x, e - emax);
        float yv[64];
        {
            const uint4* yq = (const uint4*)yl;
#pragma unroll
            for (int i = 0; i < 16; ++i) {
                union { uint4 u; float f[4]; } cv;
                cv.u = yq[i];
                yv[4 * i + 0] = cv.f[0]; yv[4 * i + 1] = cv.f[1];
                yv[4 * i + 2] = cv.f[2]; yv[4 * i + 3] = cv.f[3];
            }
        }
        const uint4* rp = (const uint4*)(Pg + ((size_t)chain * CC + c) * 4096 + (size_t)j * TT);
        float acc = 0.f;
#pragma unroll
        for (int i = 0; i < 8; ++i) {
            union { uint4 u; _Float16 h[8]; } pv;
            pv.u = rp[i];
#pragma unroll
            for (int k2 = 0; k2 < 8; ++k2)
                acc = __builtin_fmaf((float)pv.h[k2], yv[8 * i + k2], acc);
        }
        float am = acc;
#pragma unroll
        for (int m = 1; m < 64; m <<= 1) am = fmaxf(am, __shfl_xor(am, m, 64));
        int e0 = (int)((__float_as_uint(am) >> 23) & 255u) - 127;
        x = ldexpf(acc, -e0);
        esumX += e0 + emax;
    }

    float val = x * expf(trans[j * TT + END_TAG]);
#pragma unroll
    for (int m = 1; m < 64; m <<= 1) val += __shfl_xor(val, m, 64);
    float fwd = logf(val) + (float)esumX * LN2_F + M0;

    if (j == 0) {
        float gold = g + trans[tags[chain * SS + L - 1] * TT + END_TAG];
        atomicAdd(out, fwd - gold);
    }
}

extern "C" void kernel_launch(void* const* d_in, const int* in_sizes, int n_in,
                              void* d_out, int out_size, void* d_ws, size_t ws_size,
                              hipStream_t stream) {
    const float* feats = (const float*)d_in[0];
    const float* trans = (const float*)d_in[1];
    const int*   mask  = (const int*)d_in[2];
    const int*   tags  = (const int*)d_in[3];
    float* out = (float*)d_out;
    unsigned short* Pg = (unsigned short*)d_ws;
    int*       Eg = (int*)((char*)d_ws + WS_ECOL_OFF);

    crf_chunks<<<dim3(64 * CC), dim3(256), 0, stream>>>(feats, trans, mask, Pg, Eg, out);
    crf_combine<<<dim3(64), dim3(64), 0, stream>>>(feats, trans, mask, tags, Pg, Eg, out);
}